// Round 15
// baseline (467.547 us; speedup 1.0000x reference)
//
#include <hip/hip_runtime.h>

#define Bn 4
#define Hn 16
#define Sn 2048
#define Dn 64
#define NT (Sn / 64)
#define BLOB 16384
#define WS_NEED ((size_t)Bn * Hn * NT * BLOB)

typedef __attribute__((ext_vector_type(8))) short bf16x8;
typedef __attribute__((ext_vector_type(8))) _Float16 f16x8;
typedef __attribute__((ext_vector_type(4))) float f32x4;
typedef __attribute__((ext_vector_type(4))) float float4_t;
typedef __attribute__((ext_vector_type(2))) unsigned u32x2;

__device__ __forceinline__ short f2bf(float f) {
    union { float f; unsigned u; } v; v.f = f;
    unsigned r = v.u + 0x7fffu + ((v.u >> 16) & 1u);
    return (short)(r >> 16);
}
__device__ __forceinline__ unsigned cvtpk_bf16(float a, float b) {
    unsigned d;
    asm("v_cvt_pk_bf16_f32 %0, %1, %2" : "=v"(d) : "v"(a), "v"(b));
    return d;
}

// ---------------- pre-pass: K -> fp16 (single), V -> V^T bf16, LDS-image layout ----------------
// blob[bh*NT + t] (16 KB): [0,8K) K fp16 swizzled, [8K,16K) V^T bf16 swizzled.
__global__ __launch_bounds__(256) void prepass_kernel(
    const float* __restrict__ K, const float* __restrict__ V, char* __restrict__ ws)
{
    const int tid = threadIdx.x;
    const int kv0 = (blockIdx.x & (NT - 1)) * 64;
    char* blob = ws + (size_t)blockIdx.x * BLOB;
    const size_t kv_base = (size_t)(blockIdx.x >> 5) * Sn * Dn;

    {
        const int r  = tid >> 2;
        const int dc = (tid & 3) * 16;
        const float* krow = K + kv_base + (size_t)(kv0 + r) * Dn + dc;
        float4_t k0 = ((const float4_t*)krow)[0];
        float4_t k1 = ((const float4_t*)krow)[1];
        float4_t k2 = ((const float4_t*)krow)[2];
        float4_t k3 = ((const float4_t*)krow)[3];
        float fv[16] = {k0[0],k0[1],k0[2],k0[3], k1[0],k1[1],k1[2],k1[3],
                        k2[0],k2[1],k2[2],k2[3], k3[0],k3[1],k3[2],k3[3]};
        f16x8 ha, hb;
#pragma unroll
        for (int j = 0; j < 8; ++j) {
            ha[j] = (_Float16)fv[j];
            hb[j] = (_Float16)fv[j + 8];
        }
        const unsigned base = (unsigned)(r * 128 + dc * 2);
        const unsigned swz  = (unsigned)((r & 7) << 4);
        *(f16x8*)(blob + ((base) ^ swz))      = ha;
        *(f16x8*)(blob + ((base + 16) ^ swz)) = hb;
    }
    {
        const int r2 = (tid & 31) * 2;
        const int d0 = (tid >> 5) * 8;
        const float* v0 = V + kv_base + (size_t)(kv0 + r2) * Dn + d0;
        float4_t a0 = ((const float4_t*)v0)[0];
        float4_t a1 = ((const float4_t*)v0)[1];
        float4_t b0 = ((const float4_t*)(v0 + Dn))[0];
        float4_t b1 = ((const float4_t*)(v0 + Dn))[1];
        float av[8] = {a0[0],a0[1],a0[2],a0[3], a1[0],a1[1],a1[2],a1[3]};
        float bv[8] = {b0[0],b0[1],b0[2],b0[3], b1[0],b1[1],b1[2],b1[3]};
#pragma unroll
        for (int j = 0; j < 8; ++j) {
            const int d = d0 + j;
            unsigned wv = ((unsigned)(unsigned short)f2bf(av[j]))
                        | (((unsigned)(unsigned short)f2bf(bv[j])) << 16);
            unsigned off = ((unsigned)(d * 128 + r2 * 2)) ^ ((unsigned)((d & 7) << 4));
            *(unsigned*)(blob + 8192 + off) = wv;
        }
    }
}

// ---------------- main attention kernel: R14 + forced 3 blocks/CU ----------------
// __launch_bounds__(512, 6): VGPR cap 85 -> 3 blocks/CU (LDS 48.5 KB x3 = 145.5 <= 160),
// 24 waves/CU. To fit spill-free, the mask regs are SINGLE-buffered: LOADMASK(T+1) is
// issued right AFTER the P-write consumes tile-T's masks (same registers reused, -16 VGPR).
// vmcnt queue at each barrier = [2 staging, 4 masks]; vmcnt(4) drains exactly the staging.
__global__ __launch_bounds__(512, 6) void attn_main_kernel(
    const float* __restrict__ Q, const float* __restrict__ Msk,
    const char* __restrict__ ws, float* __restrict__ Out)
{
    __shared__ char lds_kv[2][BLOB];               // double-buffered tile blob (shared by 8 waves)
    __shared__ unsigned short lds_p[8][16 * 64];   // per-wave P tile (wave-private)
    __shared__ float lds_l[8][16];                 // per-wave denom redistribute (epilogue)

    const int tid  = threadIdx.x;
    const int lane = tid & 63;
    const int w    = tid >> 6;        // 0..7
    const int lq   = lane & 15;
    const int lg   = lane >> 4;

    const int bh = blockIdx.x;        // bh-major: XCD = bh % 8
    const int q0 = blockIdx.y * 128;  // 128 q-rows per block

    const float* qp   = Q + (size_t)bh * Sn * Dn;
    const float* mrow = Msk + (size_t)bh * Sn * Sn + (size_t)(q0 + w * 16 + lq) * Sn;
    const char* ws_bh = ws + (size_t)bh * NT * BLOB;
    float* op = Out + (size_t)bh * Sn * Dn + (size_t)(q0 + w * 16) * Dn;

    const float QSCALE = 2.0402789f;  // sqrt(2) * log2(e): logits directly in log2 domain

    // ---- Q fragments, single fp16, pre-scaled (MFMA B operand) ----
    f16x8 qf[2];
    {
        const float* qrow = qp + (size_t)(q0 + w * 16 + lq) * Dn + lg * 8;
#pragma unroll
        for (int c = 0; c < 2; ++c) {
            float4_t f0 = *(const float4_t*)(qrow + c * 32);
            float4_t f1 = *(const float4_t*)(qrow + c * 32 + 4);
            float fv[8] = {f0[0], f0[1], f0[2], f0[3], f1[0], f1[1], f1[2], f1[3]};
            f16x8 tf;
#pragma unroll
            for (int j = 0; j < 8; ++j) tf[j] = (_Float16)(fv[j] * QSCALE);
            qf[c] = tf;
        }
    }

    float l_acc = 0.0f;   // per-lane partial denominator for q = lq
    f32x4 o_acc[4];
#pragma unroll
    for (int dt = 0; dt < 4; ++dt) o_acc[dt] = (f32x4){0.f, 0.f, 0.f, 0.f};

// 8 waves x 2 KB each = 16 KB blob
#define STAGE(TSRC, BUFIDX) do {                                                   \
        const char* _src = ws_bh + (size_t)(TSRC) * BLOB + w * 2048 + lane * 16;   \
        char* _dst = &lds_kv[BUFIDX][w * 2048];                                    \
        _Pragma("unroll")                                                          \
        for (int _i = 0; _i < 2; ++_i) {                                           \
            __builtin_amdgcn_global_load_lds(                                      \
                (const __attribute__((address_space(1))) void*)(_src + _i * 1024), \
                (__attribute__((address_space(3))) void*)(_dst + _i * 1024),       \
                16, 0, 0);                                                         \
        }                                                                          \
    } while (0)

// mask[q=lq][kv = T*64 + kt*16 + lg*4 .. +3] as one dwordx4 per kt
#define LOADMASK(MREG, TSRC) do {                                                  \
        _Pragma("unroll")                                                          \
        for (int _kt = 0; _kt < 4; ++_kt)                                          \
            MREG[_kt] = *(const float4_t*)(mrow + (TSRC) * 64 + _kt * 16 + lg * 4);\
    } while (0)

// counted barrier: drain staging (2 oldest VMEM), keep 4 mask loads in flight
#define TILE_BARRIER() do {                                                        \
        asm volatile("s_waitcnt vmcnt(4)\n\ts_barrier" ::: "memory");              \
        __builtin_amdgcn_sched_barrier(0);                                         \
    } while (0)

#define ITER_BODY(T, BUF, MU) do {                                                       \
        TILE_BARRIER(); /* staging(T) drained; mask(T) still in flight */                \
        if ((T) + 1 < NT) {                                                              \
            STAGE((T) + 1, (BUF) ^ 1);                                                   \
            __builtin_amdgcn_sched_barrier(0); /* pin: staging issued here */            \
        }                                                                                \
        const char* kb = lds_kv[BUF];                                                    \
        f32x4 s[4];                                                                      \
        _Pragma("unroll")                                                                \
        for (int kt = 0; kt < 4; ++kt) {                                                 \
            f32x4 acc = (f32x4){0.f, 0.f, 0.f, 0.f};                                     \
            _Pragma("unroll")                                                            \
            for (int c = 0; c < 2; ++c) {                                                \
                const int krow = kt * 16 + lq;                                           \
                unsigned off = ((unsigned)(krow * 128 + (c * 32 + lg * 8) * 2))          \
                             ^ ((unsigned)((krow & 7) << 4));                            \
                f16x8 khf = *(const f16x8*)(kb + off);                                   \
                /* swapped operands: S^T = K * Q^T, single fp16 MFMA */                  \
                acc = __builtin_amdgcn_mfma_f32_16x16x32_f16(khf, qf[c], acc, 0, 0, 0);  \
            }                                                                            \
            s[kt] = acc;                                                                 \
        }                                                                                \
        /* fixed-base softmax numerator + mask -> P (4 consecutive kv per kt, b64) */    \
        {                                                                                \
            unsigned short* pw = &lds_p[w][0];                                           \
            const unsigned pswz = (unsigned)((lq & 7) << 4);                             \
            _Pragma("unroll")                                                            \
            for (int kt = 0; kt < 4; ++kt) {                                             \
                float p0 = exp2f(s[kt][0]);                                              \
                float p1 = exp2f(s[kt][1]);                                              \
                float p2 = exp2f(s[kt][2]);                                              \
                float p3 = exp2f(s[kt][3]);                                              \
                l_acc += (p0 + p1) + (p2 + p3);                                          \
                unsigned w0 = cvtpk_bf16(p0 * MU[kt][0], p1 * MU[kt][1]);                \
                unsigned w1 = cvtpk_bf16(p2 * MU[kt][2], p3 * MU[kt][3]);                \
                unsigned off = ((unsigned)(lq * 128 + kt * 32 + lg * 8)) ^ pswz;         \
                u32x2 wv; wv[0] = w0; wv[1] = w1;                                        \
                *(u32x2*)((char*)pw + off) = wv;                                         \
            }                                                                            \
        }                                                                                \
        /* masks of tile T consumed -> reuse the SAME registers for tile T+1 */          \
        if ((T) + 1 < NT) {                                                              \
            LOADMASK(MU, (T) + 1);                                                       \
            __builtin_amdgcn_sched_barrier(0); /* pin: mask loads issued here */         \
        }                                                                                \
        /* PV (bf16): P from wave-private LDS (b128), V^T frags from shared blob */      \
        _Pragma("unroll")                                                                \
        for (int kc = 0; kc < 2; ++kc) {                                                 \
            unsigned poff = ((unsigned)(lq * 128 + (kc * 32 + lg * 8) * 2))              \
                          ^ ((unsigned)((lq & 7) << 4));                                 \
            bf16x8 pa = *(const bf16x8*)((const char*)&lds_p[w][0] + poff);              \
            _Pragma("unroll")                                                            \
            for (int dt = 0; dt < 4; ++dt) {                                             \
                const int drow = dt * 16 + lq;                                           \
                unsigned voff = 8192 +                                                   \
                    (((unsigned)(drow * 128 + (kc * 32 + lg * 8) * 2))                   \
                     ^ ((unsigned)((drow & 7) << 4)));                                   \
                bf16x8 vb = *(const bf16x8*)(kb + voff);                                 \
                o_acc[dt] = __builtin_amdgcn_mfma_f32_16x16x32_bf16(pa, vb, o_acc[dt],   \
                                                                    0, 0, 0);            \
            }                                                                            \
        }                                                                                \
    } while (0)

    float4_t mA[4];
    STAGE(0, 0);
    __builtin_amdgcn_sched_barrier(0);
    LOADMASK(mA, 0);
    __builtin_amdgcn_sched_barrier(0);

    for (int t = 0; t < NT; t += 2) {
        ITER_BODY(t, 0, mA);
        ITER_BODY(t + 1, 1, mA);
    }

    // ---- epilogue: l lives at q=lq; reduce across lg, redistribute to o_acc rows ----
    l_acc += __shfl_xor(l_acc, 16);
    l_acc += __shfl_xor(l_acc, 32);
    if (lane < 16) lds_l[w][lane] = l_acc;
    __builtin_amdgcn_sched_barrier(0);
#pragma unroll
    for (int r = 0; r < 4; ++r) {
        const float inv = 1.0f / lds_l[w][lg * 4 + r];
#pragma unroll
        for (int dt = 0; dt < 4; ++dt) {
            op[(size_t)(lg * 4 + r) * Dn + dt * 16 + lq] = o_acc[dt][r] * inv;
        }
    }
#undef STAGE
#undef LOADMASK
#undef TILE_BARRIER
#undef ITER_BODY
}

// ---------------- fallback (self-contained, used if ws too small) ----------------
__global__ __launch_bounds__(256) void attn_drop_fallback(
    const float* __restrict__ Q, const float* __restrict__ K,
    const float* __restrict__ V, const float* __restrict__ Msk,
    float* __restrict__ Out)
{
    __shared__ unsigned short lds_kf[64 * 64];
    __shared__ unsigned short lds_v[64 * 64];
    __shared__ unsigned short lds_p[4][16 * 64];

    const int tid  = threadIdx.x;
    const int lane = tid & 63;
    const int w    = tid >> 6;
    const int lq   = lane & 15;
    const int lg   = lane >> 4;
    const int q0 = blockIdx.x * 64;
    const int bh = blockIdx.y;
    const size_t qkv_base = (size_t)bh * Sn * Dn;
    const float* qp = Q + qkv_base;
    const float* kp = K + qkv_base;
    const float* vp = V + qkv_base;
    const float* mbase = Msk + (size_t)bh * Sn * Sn + (size_t)(q0 + w * 16) * Sn;
    float* op = Out + qkv_base + (size_t)(q0 + w * 16) * Dn;
    const float QSCALE = 2.0402789f;

    f16x8 qf[2];
    {
        const float* qrow = qp + (size_t)(q0 + w * 16 + lq) * Dn + lg * 8;
#pragma unroll
        for (int c = 0; c < 2; ++c) {
            float4_t f0 = *(const float4_t*)(qrow + c * 32);
            float4_t f1 = *(const float4_t*)(qrow + c * 32 + 4);
            float fv[8] = {f0[0], f0[1], f0[2], f0[3], f1[0], f1[1], f1[2], f1[3]};
            f16x8 tf;
#pragma unroll
            for (int j = 0; j < 8; ++j) tf[j] = (_Float16)(fv[j] * QSCALE);
            qf[c] = tf;
        }
    }
    float l_st = 0.0f;
    f32x4 o_acc[4];
#pragma unroll
    for (int dt = 0; dt < 4; ++dt) o_acc[dt] = (f32x4){0.f, 0.f, 0.f, 0.f};

    for (int t = 0; t < NT; ++t) {
        const int kv0 = t * 64;
        __syncthreads();
        {
            const int r  = tid >> 2;
            const int dc = (tid & 3) * 16;
            const float* krow = kp + (size_t)(kv0 + r) * Dn + dc;
            float4_t k0 = ((const float4_t*)krow)[0];
            float4_t k1 = ((const float4_t*)krow)[1];
            float4_t k2 = ((const float4_t*)krow)[2];
            float4_t k3 = ((const float4_t*)krow)[3];
            float fv[16] = {k0[0],k0[1],k0[2],k0[3], k1[0],k1[1],k1[2],k1[3],
                            k2[0],k2[1],k2[2],k2[3], k3[0],k3[1],k3[2],k3[3]};
            f16x8 ha, hb;
#pragma unroll
            for (int j = 0; j < 8; ++j) {
                ha[j] = (_Float16)fv[j];
                hb[j] = (_Float16)fv[j + 8];
            }
            const unsigned base = (unsigned)(r * 128 + dc * 2);
            const unsigned swz  = (unsigned)((r & 7) << 4);
            *(f16x8*)((char*)lds_kf + ((base) ^ swz))      = ha;
            *(f16x8*)((char*)lds_kf + ((base + 16) ^ swz)) = hb;
        }
        {
            const int r2 = (tid & 31) * 2;
            const int d0 = (tid >> 5) * 8;
            const float* v0 = vp + (size_t)(kv0 + r2) * Dn + d0;
            float4_t a0 = ((const float4_t*)v0)[0];
            float4_t a1 = ((const float4_t*)v0)[1];
            float4_t b0 = ((const float4_t*)(v0 + Dn))[0];
            float4_t b1 = ((const float4_t*)(v0 + Dn))[1];
            float av[8] = {a0[0],a0[1],a0[2],a0[3], a1[0],a1[1],a1[2],a1[3]};
            float bv[8] = {b0[0],b0[1],b0[2],b0[3], b1[0],b1[1],b1[2],b1[3]};
#pragma unroll
            for (int j = 0; j < 8; ++j) {
                const int d = d0 + j;
                unsigned wv = ((unsigned)(unsigned short)f2bf(av[j]))
                            | (((unsigned)(unsigned short)f2bf(bv[j])) << 16);
                unsigned off = ((unsigned)(d * 128 + r2 * 2)) ^ ((unsigned)((d & 7) << 4));
                *(unsigned*)((char*)lds_v + off) = wv;
            }
        }
        __syncthreads();
        f32x4 s[4];
#pragma unroll
        for (int kt = 0; kt < 4; ++kt) {
            f32x4 acc = (f32x4){0.f, 0.f, 0.f, 0.f};
#pragma unroll
            for (int c = 0; c < 2; ++c) {
                const int krow = kt * 16 + lq;
                unsigned off = ((unsigned)(krow * 128 + (c * 32 + lg * 8) * 2))
                             ^ ((unsigned)((krow & 7) << 4));
                f16x8 khf = *(const f16x8*)((const char*)lds_kf + off);
                acc = __builtin_amdgcn_mfma_f32_16x16x32_f16(khf, qf[c], acc, 0, 0, 0);
            }
            s[kt] = acc;
        }
        // swapped operands -> lane holds q=lq, kv=kt*16+lg*4+r
        {
            unsigned short* pw = &lds_p[w][0];
            const unsigned pswz = (unsigned)((lq & 7) << 4);
            const float* mp = mbase + (size_t)lq * Sn + kv0;
#pragma unroll
            for (int kt = 0; kt < 4; ++kt) {
                float e0 = exp2f(s[kt][0]);
                float e1 = exp2f(s[kt][1]);
                float e2 = exp2f(s[kt][2]);
                float e3 = exp2f(s[kt][3]);
                l_st += (e0 + e1) + (e2 + e3);
                float p0 = e0 * mp[kt * 16 + lg * 4 + 0];
                float p1 = e1 * mp[kt * 16 + lg * 4 + 1];
                float p2 = e2 * mp[kt * 16 + lg * 4 + 2];
                float p3 = e3 * mp[kt * 16 + lg * 4 + 3];
                unsigned w0 = cvtpk_bf16(p0, p1);
                unsigned w1 = cvtpk_bf16(p2, p3);
                unsigned off = ((unsigned)(lq * 128 + kt * 32 + lg * 8)) ^ pswz;
                u32x2 wv; wv[0] = w0; wv[1] = w1;
                *(u32x2*)((char*)pw + off) = wv;
            }
        }
        __syncthreads();
#pragma unroll
        for (int kc = 0; kc < 2; ++kc) {
            unsigned poff = ((unsigned)(lq * 128 + (kc * 32 + lg * 8) * 2))
                          ^ ((unsigned)((lq & 7) << 4));
            bf16x8 pa = *(const bf16x8*)((const char*)&lds_p[w][0] + poff);
#pragma unroll
            for (int dt = 0; dt < 4; ++dt) {
                const int drow = dt * 16 + lq;
                unsigned voff = ((unsigned)(drow * 128 + (kc * 32 + lg * 8) * 2))
                              ^ ((unsigned)((drow & 7) << 4));
                bf16x8 vb = *(const bf16x8*)((const char*)lds_v + voff);
                o_acc[dt] = __builtin_amdgcn_mfma_f32_16x16x32_bf16(pa, vb, o_acc[dt], 0, 0, 0);
            }
        }
    }
    {
        float l_acc = l_st;
        l_acc += __shfl_xor(l_acc, 16);
        l_acc += __shfl_xor(l_acc, 32);
        __shared__ float lds_l[4][16];
        if (lane < 16) lds_l[w][lane] = l_acc;
        __syncthreads();
#pragma unroll
        for (int r = 0; r < 4; ++r) {
            const float inv = 1.0f / lds_l[w][lg * 4 + r];
#pragma unroll
            for (int dt = 0; dt < 4; ++dt) {
                op[(size_t)(lg * 4 + r) * Dn + dt * 16 + lq] = o_acc[dt][r] * inv;
            }
        }
    }
}

extern "C" void kernel_launch(void* const* d_in, const int* in_sizes, int n_in,
                              void* d_out, int out_size, void* d_ws, size_t ws_size,
                              hipStream_t stream) {
    const float* q   = (const float*)d_in[0];
    const float* k   = (const float*)d_in[1];
    const float* v   = (const float*)d_in[2];
    const float* msk = (const float*)d_in[3];
    float* out = (float*)d_out;

    if (ws_size >= WS_NEED) {
        prepass_kernel<<<dim3(Bn * Hn * NT), dim3(256), 0, stream>>>(k, v, (char*)d_ws);
        attn_main_kernel<<<dim3(Bn * Hn, Sn / 128), dim3(512), 0, stream>>>(
            q, msk, (const char*)d_ws, out);
    } else {
        attn_drop_fallback<<<dim3(Sn / 64, Bn * Hn), dim3(256), 0, stream>>>(
            q, k, v, msk, out);
    }
}

// Round 16
// 313.116 us; speedup vs baseline: 1.4932x; 1.4932x over previous
//
#include <hip/hip_runtime.h>

#define Bn 4
#define Hn 16
#define Sn 2048
#define Dn 64
#define NT (Sn / 64)
#define BLOB 16384
#define WS_NEED ((size_t)Bn * Hn * NT * BLOB)

typedef __attribute__((ext_vector_type(8))) short bf16x8;
typedef __attribute__((ext_vector_type(8))) _Float16 f16x8;
typedef __attribute__((ext_vector_type(4))) float f32x4;
typedef __attribute__((ext_vector_type(4))) float float4_t;
typedef __attribute__((ext_vector_type(2))) unsigned u32x2;

__device__ __forceinline__ short f2bf(float f) {
    union { float f; unsigned u; } v; v.f = f;
    unsigned r = v.u + 0x7fffu + ((v.u >> 16) & 1u);
    return (short)(r >> 16);
}
__device__ __forceinline__ unsigned cvtpk_bf16(float a, float b) {
    unsigned d;
    asm("v_cvt_pk_bf16_f32 %0, %1, %2" : "=v"(d) : "v"(a), "v"(b));
    return d;
}

// ---------------- pre-pass: K -> fp16 (single), V -> V^T bf16, LDS-image layout ----------------
// blob[bh*NT + t] (16 KB): [0,8K) K fp16 swizzled, [8K,16K) V^T bf16 swizzled.
__global__ __launch_bounds__(256) void prepass_kernel(
    const float* __restrict__ K, const float* __restrict__ V, char* __restrict__ ws)
{
    const int tid = threadIdx.x;
    const int kv0 = (blockIdx.x & (NT - 1)) * 64;
    char* blob = ws + (size_t)blockIdx.x * BLOB;
    const size_t kv_base = (size_t)(blockIdx.x >> 5) * Sn * Dn;

    {
        const int r  = tid >> 2;
        const int dc = (tid & 3) * 16;
        const float* krow = K + kv_base + (size_t)(kv0 + r) * Dn + dc;
        float4_t k0 = ((const float4_t*)krow)[0];
        float4_t k1 = ((const float4_t*)krow)[1];
        float4_t k2 = ((const float4_t*)krow)[2];
        float4_t k3 = ((const float4_t*)krow)[3];
        float fv[16] = {k0[0],k0[1],k0[2],k0[3], k1[0],k1[1],k1[2],k1[3],
                        k2[0],k2[1],k2[2],k2[3], k3[0],k3[1],k3[2],k3[3]};
        f16x8 ha, hb;
#pragma unroll
        for (int j = 0; j < 8; ++j) {
            ha[j] = (_Float16)fv[j];
            hb[j] = (_Float16)fv[j + 8];
        }
        const unsigned base = (unsigned)(r * 128 + dc * 2);
        const unsigned swz  = (unsigned)((r & 7) << 4);
        *(f16x8*)(blob + ((base) ^ swz))      = ha;
        *(f16x8*)(blob + ((base + 16) ^ swz)) = hb;
    }
    {
        const int r2 = (tid & 31) * 2;
        const int d0 = (tid >> 5) * 8;
        const float* v0 = V + kv_base + (size_t)(kv0 + r2) * Dn + d0;
        float4_t a0 = ((const float4_t*)v0)[0];
        float4_t a1 = ((const float4_t*)v0)[1];
        float4_t b0 = ((const float4_t*)(v0 + Dn))[0];
        float4_t b1 = ((const float4_t*)(v0 + Dn))[1];
        float av[8] = {a0[0],a0[1],a0[2],a0[3], a1[0],a1[1],a1[2],a1[3]};
        float bv[8] = {b0[0],b0[1],b0[2],b0[3], b1[0],b1[1],b1[2],b1[3]};
#pragma unroll
        for (int j = 0; j < 8; ++j) {
            const int d = d0 + j;
            unsigned wv = ((unsigned)(unsigned short)f2bf(av[j]))
                        | (((unsigned)(unsigned short)f2bf(bv[j])) << 16);
            unsigned off = ((unsigned)(d * 128 + r2 * 2)) ^ ((unsigned)((d & 7) << 4));
            *(unsigned*)(blob + 8192 + off) = wv;
        }
    }
}

// ---------------- main attention kernel: R14 (315 us) + s_setprio around MFMA clusters ----------------
// 8 waves/512 threads share one staged 16 KB blob; swapped S^T QK (single fp16 MFMA);
// fixed-base softmax; cvt_pk bf16 P-writes; PV in bf16; counted-vmcnt barrier;
// double-buffered mask regs (1 tile ahead). launch_bounds(512,4) as in R14.
__global__ __launch_bounds__(512, 4) void attn_main_kernel(
    const float* __restrict__ Q, const float* __restrict__ Msk,
    const char* __restrict__ ws, float* __restrict__ Out)
{
    __shared__ char lds_kv[2][BLOB];               // double-buffered tile blob (shared by 8 waves)
    __shared__ unsigned short lds_p[8][16 * 64];   // per-wave P tile (wave-private)
    __shared__ float lds_l[8][16];                 // per-wave denom redistribute (epilogue)

    const int tid  = threadIdx.x;
    const int lane = tid & 63;
    const int w    = tid >> 6;        // 0..7
    const int lq   = lane & 15;
    const int lg   = lane >> 4;

    const int bh = blockIdx.x;        // bh-major: XCD = bh % 8
    const int q0 = blockIdx.y * 128;  // 128 q-rows per block

    const float* qp   = Q + (size_t)bh * Sn * Dn;
    const float* mrow = Msk + (size_t)bh * Sn * Sn + (size_t)(q0 + w * 16 + lq) * Sn;
    const char* ws_bh = ws + (size_t)bh * NT * BLOB;
    float* op = Out + (size_t)bh * Sn * Dn + (size_t)(q0 + w * 16) * Dn;

    const float QSCALE = 2.0402789f;  // sqrt(2) * log2(e): logits directly in log2 domain

    // ---- Q fragments, single fp16, pre-scaled (MFMA B operand) ----
    f16x8 qf[2];
    {
        const float* qrow = qp + (size_t)(q0 + w * 16 + lq) * Dn + lg * 8;
#pragma unroll
        for (int c = 0; c < 2; ++c) {
            float4_t f0 = *(const float4_t*)(qrow + c * 32);
            float4_t f1 = *(const float4_t*)(qrow + c * 32 + 4);
            float fv[8] = {f0[0], f0[1], f0[2], f0[3], f1[0], f1[1], f1[2], f1[3]};
            f16x8 tf;
#pragma unroll
            for (int j = 0; j < 8; ++j) tf[j] = (_Float16)(fv[j] * QSCALE);
            qf[c] = tf;
        }
    }

    float l_acc = 0.0f;   // per-lane partial denominator for q = lq
    f32x4 o_acc[4];
#pragma unroll
    for (int dt = 0; dt < 4; ++dt) o_acc[dt] = (f32x4){0.f, 0.f, 0.f, 0.f};

// 8 waves x 2 KB each = 16 KB blob
#define STAGE(TSRC, BUFIDX) do {                                                   \
        const char* _src = ws_bh + (size_t)(TSRC) * BLOB + w * 2048 + lane * 16;   \
        char* _dst = &lds_kv[BUFIDX][w * 2048];                                    \
        _Pragma("unroll")                                                          \
        for (int _i = 0; _i < 2; ++_i) {                                           \
            __builtin_amdgcn_global_load_lds(                                      \
                (const __attribute__((address_space(1))) void*)(_src + _i * 1024), \
                (__attribute__((address_space(3))) void*)(_dst + _i * 1024),       \
                16, 0, 0);                                                         \
        }                                                                          \
    } while (0)

// mask[q=lq][kv = T*64 + kt*16 + lg*4 .. +3] as one dwordx4 per kt
#define LOADMASK(MREG, TSRC) do {                                                  \
        _Pragma("unroll")                                                          \
        for (int _kt = 0; _kt < 4; ++_kt)                                          \
            MREG[_kt] = *(const float4_t*)(mrow + (TSRC) * 64 + _kt * 16 + lg * 4);\
    } while (0)

// counted barrier: drain staging (2 oldest VMEM), keep 4 mask loads in flight
#define TILE_BARRIER() do {                                                        \
        asm volatile("s_waitcnt vmcnt(4)\n\ts_barrier" ::: "memory");              \
        __builtin_amdgcn_sched_barrier(0);                                         \
    } while (0)

#define ITER_BODY(T, BUF, MU, MP) do {                                                   \
        TILE_BARRIER(); /* staging(T) drained; mask(T) still in flight */                \
        if ((T) + 1 < NT) {                                                              \
            STAGE((T) + 1, (BUF) ^ 1);                                                   \
            __builtin_amdgcn_sched_barrier(0); /* pin: staging before mask loads */      \
            LOADMASK(MP, (T) + 1);                                                       \
            __builtin_amdgcn_sched_barrier(0); /* pin: mask loads issued here */         \
        }                                                                                \
        const char* kb = lds_kv[BUF];                                                    \
        f32x4 s[4];                                                                      \
        __builtin_amdgcn_s_setprio(1);                                                   \
        _Pragma("unroll")                                                                \
        for (int kt = 0; kt < 4; ++kt) {                                                 \
            f32x4 acc = (f32x4){0.f, 0.f, 0.f, 0.f};                                     \
            _Pragma("unroll")                                                            \
            for (int c = 0; c < 2; ++c) {                                                \
                const int krow = kt * 16 + lq;                                           \
                unsigned off = ((unsigned)(krow * 128 + (c * 32 + lg * 8) * 2))          \
                             ^ ((unsigned)((krow & 7) << 4));                            \
                f16x8 khf = *(const f16x8*)(kb + off);                                   \
                /* swapped operands: S^T = K * Q^T, single fp16 MFMA */                  \
                acc = __builtin_amdgcn_mfma_f32_16x16x32_f16(khf, qf[c], acc, 0, 0, 0);  \
            }                                                                            \
            s[kt] = acc;                                                                 \
        }                                                                                \
        __builtin_amdgcn_s_setprio(0);                                                   \
        /* fixed-base softmax numerator + mask -> P (4 consecutive kv per kt, b64) */    \
        {                                                                                \
            unsigned short* pw = &lds_p[w][0];                                           \
            const unsigned pswz = (unsigned)((lq & 7) << 4);                             \
            _Pragma("unroll")                                                            \
            for (int kt = 0; kt < 4; ++kt) {                                             \
                float p0 = exp2f(s[kt][0]);                                              \
                float p1 = exp2f(s[kt][1]);                                              \
                float p2 = exp2f(s[kt][2]);                                              \
                float p3 = exp2f(s[kt][3]);                                              \
                l_acc += (p0 + p1) + (p2 + p3);                                          \
                unsigned w0 = cvtpk_bf16(p0 * MU[kt][0], p1 * MU[kt][1]);                \
                unsigned w1 = cvtpk_bf16(p2 * MU[kt][2], p3 * MU[kt][3]);                \
                unsigned off = ((unsigned)(lq * 128 + kt * 32 + lg * 8)) ^ pswz;         \
                u32x2 wv; wv[0] = w0; wv[1] = w1;                                        \
                *(u32x2*)((char*)pw + off) = wv;                                         \
            }                                                                            \
        }                                                                                \
        /* PV (bf16): P from wave-private LDS (b128), V^T frags from shared blob */      \
        __builtin_amdgcn_s_setprio(1);                                                   \
        _Pragma("unroll")                                                                \
        for (int kc = 0; kc < 2; ++kc) {                                                 \
            unsigned poff = ((unsigned)(lq * 128 + (kc * 32 + lg * 8) * 2))              \
                          ^ ((unsigned)((lq & 7) << 4));                                 \
            bf16x8 pa = *(const bf16x8*)((const char*)&lds_p[w][0] + poff);              \
            _Pragma("unroll")                                                            \
            for (int dt = 0; dt < 4; ++dt) {                                             \
                const int drow = dt * 16 + lq;                                           \
                unsigned voff = 8192 +                                                   \
                    (((unsigned)(drow * 128 + (kc * 32 + lg * 8) * 2))                   \
                     ^ ((unsigned)((drow & 7) << 4)));                                   \
                bf16x8 vb = *(const bf16x8*)(kb + voff);                                 \
                o_acc[dt] = __builtin_amdgcn_mfma_f32_16x16x32_bf16(pa, vb, o_acc[dt],   \
                                                                    0, 0, 0);            \
            }                                                                            \
        }                                                                                \
        __builtin_amdgcn_s_setprio(0);                                                   \
    } while (0)

    float4_t mA[4], mB[4];
    STAGE(0, 0);
    __builtin_amdgcn_sched_barrier(0);
    LOADMASK(mA, 0);
    __builtin_amdgcn_sched_barrier(0);

    for (int t = 0; t < NT; t += 2) {
        ITER_BODY(t, 0, mA, mB);
        ITER_BODY(t + 1, 1, mB, mA);
    }

    // ---- epilogue: l lives at q=lq; reduce across lg, redistribute to o_acc rows ----
    l_acc += __shfl_xor(l_acc, 16);
    l_acc += __shfl_xor(l_acc, 32);
    if (lane < 16) lds_l[w][lane] = l_acc;
    __builtin_amdgcn_sched_barrier(0);
#pragma unroll
    for (int r = 0; r < 4; ++r) {
        const float inv = 1.0f / lds_l[w][lg * 4 + r];
#pragma unroll
        for (int dt = 0; dt < 4; ++dt) {
            op[(size_t)(lg * 4 + r) * Dn + dt * 16 + lq] = o_acc[dt][r] * inv;
        }
    }
#undef STAGE
#undef LOADMASK
#undef TILE_BARRIER
#undef ITER_BODY
}

// ---------------- fallback (self-contained, used if ws too small) ----------------
__global__ __launch_bounds__(256) void attn_drop_fallback(
    const float* __restrict__ Q, const float* __restrict__ K,
    const float* __restrict__ V, const float* __restrict__ Msk,
    float* __restrict__ Out)
{
    __shared__ unsigned short lds_kf[64 * 64];
    __shared__ unsigned short lds_v[64 * 64];
    __shared__ unsigned short lds_p[4][16 * 64];

    const int tid  = threadIdx.x;
    const int lane = tid & 63;
    const int w    = tid >> 6;
    const int lq   = lane & 15;
    const int lg   = lane >> 4;
    const int q0 = blockIdx.x * 64;
    const int bh = blockIdx.y;
    const size_t qkv_base = (size_t)bh * Sn * Dn;
    const float* qp = Q + qkv_base;
    const float* kp = K + qkv_base;
    const float* vp = V + qkv_base;
    const float* mbase = Msk + (size_t)bh * Sn * Sn + (size_t)(q0 + w * 16) * Sn;
    float* op = Out + qkv_base + (size_t)(q0 + w * 16) * Dn;
    const float QSCALE = 2.0402789f;

    f16x8 qf[2];
    {
        const float* qrow = qp + (size_t)(q0 + w * 16 + lq) * Dn + lg * 8;
#pragma unroll
        for (int c = 0; c < 2; ++c) {
            float4_t f0 = *(const float4_t*)(qrow + c * 32);
            float4_t f1 = *(const float4_t*)(qrow + c * 32 + 4);
            float fv[8] = {f0[0], f0[1], f0[2], f0[3], f1[0], f1[1], f1[2], f1[3]};
            f16x8 tf;
#pragma unroll
            for (int j = 0; j < 8; ++j) tf[j] = (_Float16)(fv[j] * QSCALE);
            qf[c] = tf;
        }
    }
    float l_st = 0.0f;
    f32x4 o_acc[4];
#pragma unroll
    for (int dt = 0; dt < 4; ++dt) o_acc[dt] = (f32x4){0.f, 0.f, 0.f, 0.f};

    for (int t = 0; t < NT; ++t) {
        const int kv0 = t * 64;
        __syncthreads();
        {
            const int r  = tid >> 2;
            const int dc = (tid & 3) * 16;
            const float* krow = kp + (size_t)(kv0 + r) * Dn + dc;
            float4_t k0 = ((const float4_t*)krow)[0];
            float4_t k1 = ((const float4_t*)krow)[1];
            float4_t k2 = ((const float4_t*)krow)[2];
            float4_t k3 = ((const float4_t*)krow)[3];
            float fv[16] = {k0[0],k0[1],k0[2],k0[3], k1[0],k1[1],k1[2],k1[3],
                            k2[0],k2[1],k2[2],k2[3], k3[0],k3[1],k3[2],k3[3]};
            f16x8 ha, hb;
#pragma unroll
            for (int j = 0; j < 8; ++j) {
                ha[j] = (_Float16)fv[j];
                hb[j] = (_Float16)fv[j + 8];
            }
            const unsigned base = (unsigned)(r * 128 + dc * 2);
            const unsigned swz  = (unsigned)((r & 7) << 4);
            *(f16x8*)((char*)lds_kf + ((base) ^ swz))      = ha;
            *(f16x8*)((char*)lds_kf + ((base + 16) ^ swz)) = hb;
        }
        {
            const int r2 = (tid & 31) * 2;
            const int d0 = (tid >> 5) * 8;
            const float* v0 = vp + (size_t)(kv0 + r2) * Dn + d0;
            float4_t a0 = ((const float4_t*)v0)[0];
            float4_t a1 = ((const float4_t*)v0)[1];
            float4_t b0 = ((const float4_t*)(v0 + Dn))[0];
            float4_t b1 = ((const float4_t*)(v0 + Dn))[1];
            float av[8] = {a0[0],a0[1],a0[2],a0[3], a1[0],a1[1],a1[2],a1[3]};
            float bv[8] = {b0[0],b0[1],b0[2],b0[3], b1[0],b1[1],b1[2],b1[3]};
#pragma unroll
            for (int j = 0; j < 8; ++j) {
                const int d = d0 + j;
                unsigned wv = ((unsigned)(unsigned short)f2bf(av[j]))
                            | (((unsigned)(unsigned short)f2bf(bv[j])) << 16);
                unsigned off = ((unsigned)(d * 128 + r2 * 2)) ^ ((unsigned)((d & 7) << 4));
                *(unsigned*)((char*)lds_v + off) = wv;
            }
        }
        __syncthreads();
        f32x4 s[4];
#pragma unroll
        for (int kt = 0; kt < 4; ++kt) {
            f32x4 acc = (f32x4){0.f, 0.f, 0.f, 0.f};
#pragma unroll
            for (int c = 0; c < 2; ++c) {
                const int krow = kt * 16 + lq;
                unsigned off = ((unsigned)(krow * 128 + (c * 32 + lg * 8) * 2))
                             ^ ((unsigned)((krow & 7) << 4));
                f16x8 khf = *(const f16x8*)((const char*)lds_kf + off);
                acc = __builtin_amdgcn_mfma_f32_16x16x32_f16(khf, qf[c], acc, 0, 0, 0);
            }
            s[kt] = acc;
        }
        // swapped operands -> lane holds q=lq, kv=kt*16+lg*4+r
        {
            unsigned short* pw = &lds_p[w][0];
            const unsigned pswz = (unsigned)((lq & 7) << 4);
            const float* mp = mbase + (size_t)lq * Sn + kv0;
#pragma unroll
            for (int kt = 0; kt < 4; ++kt) {
                float e0 = exp2f(s[kt][0]);
                float e1 = exp2f(s[kt][1]);
                float e2 = exp2f(s[kt][2]);
                float e3 = exp2f(s[kt][3]);
                l_st += (e0 + e1) + (e2 + e3);
                float p0 = e0 * mp[kt * 16 + lg * 4 + 0];
                float p1 = e1 * mp[kt * 16 + lg * 4 + 1];
                float p2 = e2 * mp[kt * 16 + lg * 4 + 2];
                float p3 = e3 * mp[kt * 16 + lg * 4 + 3];
                unsigned w0 = cvtpk_bf16(p0, p1);
                unsigned w1 = cvtpk_bf16(p2, p3);
                unsigned off = ((unsigned)(lq * 128 + kt * 32 + lg * 8)) ^ pswz;
                u32x2 wv; wv[0] = w0; wv[1] = w1;
                *(u32x2*)((char*)pw + off) = wv;
            }
        }
        __syncthreads();
#pragma unroll
        for (int kc = 0; kc < 2; ++kc) {
            unsigned poff = ((unsigned)(lq * 128 + (kc * 32 + lg * 8) * 2))
                          ^ ((unsigned)((lq & 7) << 4));
            bf16x8 pa = *(const bf16x8*)((const char*)&lds_p[w][0] + poff);
#pragma unroll
            for (int dt = 0; dt < 4; ++dt) {
                const int drow = dt * 16 + lq;
                unsigned voff = ((unsigned)(drow * 128 + (kc * 32 + lg * 8) * 2))
                              ^ ((unsigned)((drow & 7) << 4));
                bf16x8 vb = *(const bf16x8*)((const char*)lds_v + voff);
                o_acc[dt] = __builtin_amdgcn_mfma_f32_16x16x32_bf16(pa, vb, o_acc[dt], 0, 0, 0);
            }
        }
    }
    {
        float l_acc = l_st;
        l_acc += __shfl_xor(l_acc, 16);
        l_acc += __shfl_xor(l_acc, 32);
        __shared__ float lds_l[4][16];
        if (lane < 16) lds_l[w][lane] = l_acc;
        __syncthreads();
#pragma unroll
        for (int r = 0; r < 4; ++r) {
            const float inv = 1.0f / lds_l[w][lg * 4 + r];
#pragma unroll
            for (int dt = 0; dt < 4; ++dt) {
                op[(size_t)(lg * 4 + r) * Dn + dt * 16 + lq] = o_acc[dt][r] * inv;
            }
        }
    }
}

extern "C" void kernel_launch(void* const* d_in, const int* in_sizes, int n_in,
                              void* d_out, int out_size, void* d_ws, size_t ws_size,
                              hipStream_t stream) {
    const float* q   = (const float*)d_in[0];
    const float* k   = (const float*)d_in[1];
    const float* v   = (const float*)d_in[2];
    const float* msk = (const float*)d_in[3];
    float* out = (float*)d_out;

    if (ws_size >= WS_NEED) {
        prepass_kernel<<<dim3(Bn * Hn * NT), dim3(256), 0, stream>>>(k, v, (char*)d_ws);
        attn_main_kernel<<<dim3(Bn * Hn, Sn / 128), dim3(512), 0, stream>>>(
            q, msk, (const char*)d_ws, out);
    } else {
        attn_drop_fallback<<<dim3(Sn / 64, Bn * Hn), dim3(256), 0, stream>>>(
            q, k, v, msk, out);
    }
}